// Round 3
// baseline (172.725 us; speedup 1.0000x reference)
//
#include <hip/hip_runtime.h>

// out[p, :] = W[i1[p], :] + (i1[p] != i2[p] ? W[i2[p], :] : 0)
// P = B*S = 32768 positions, D = 512 fp32 -> 128 float4 per row.
// One thread per output float4; threads [0..127] of each pair share a position,
// so each 64-lane wave has wave-uniform indices -> scalarized via readfirstlane.
// Output is streamed with non-temporal stores to keep L2/L3 for weight rows.

#define QUADS_PER_ROW 128   // 512 / 4

typedef float f32x4 __attribute__((ext_vector_type(4)));  // native vec: OK for nontemporal builtin

__global__ __launch_bounds__(256) void twohot_kernel(
    const int* __restrict__ idx1,
    const int* __restrict__ idx2,
    const f32x4* __restrict__ w4,   // [VOCAB * 128]
    f32x4* __restrict__ out4,       // [P * 128]
    int total_quads)
{
    int gid = blockIdx.x * blockDim.x + threadIdx.x;
    if (gid >= total_quads) return;

    int pos = gid >> 7;          // gid / 128 — uniform across each wave
    int q   = gid & (QUADS_PER_ROW - 1);

    // Indices are identical for all 64 lanes of this wave: force SGPR.
    int i1 = __builtin_amdgcn_readfirstlane(idx1[pos]);
    int i2 = __builtin_amdgcn_readfirstlane(idx2[pos]);

    f32x4 v = w4[(long)i1 * QUADS_PER_ROW + q];
    if (i2 != i1) {
        f32x4 v2 = w4[(long)i2 * QUADS_PER_ROW + q];
        v += v2;
    }
    // Write-once output: stream past L2/L3 so gathered weight rows stay cached.
    __builtin_nontemporal_store(v, &out4[gid]);
}

extern "C" void kernel_launch(void* const* d_in, const int* in_sizes, int n_in,
                              void* d_out, int out_size, void* d_ws, size_t ws_size,
                              hipStream_t stream) {
    const int*   idx1 = (const int*)d_in[0];    // input_one [B,S] int32
    const int*   idx2 = (const int*)d_in[1];    // input_two [B,S] int32
    const f32x4* w4   = (const f32x4*)d_in[2];  // weight [VOCAB, 512] fp32
    f32x4* out4       = (f32x4*)d_out;          // [B,S,512] fp32

    int total_quads = out_size / 4;              // B*S*128
    int block = 256;
    int grid  = (total_quads + block - 1) / block;
    twohot_kernel<<<grid, block, 0, stream>>>(idx1, idx2, w4, out4, total_quads);
}

// Round 4
// 172.557 us; speedup vs baseline: 1.0010x; 1.0010x over previous
//
#include <hip/hip_runtime.h>

// out[p, :] = W[i1[p], :] + (i1[p] != i2[p] ? W[i2[p], :] : 0)
// P = B*S = 32768 positions, D = 512 fp32 -> 128 float4 per row.
// One thread per TWO float4s of a position (q and q+64): a 64-lane wave covers
// a full 2 KB weight row, issuing 4 independent coalesced 1 KB loads -> 2x MLP
// vs the 1-quad/thread version. Indices are wave-uniform -> SGPR via
// readfirstlane; second-row gather is a wave-uniform branch.

#define QUADS_PER_ROW 128   // 512 / 4

typedef float f32x4 __attribute__((ext_vector_type(4)));

__global__ __launch_bounds__(256) void twohot_kernel(
    const int* __restrict__ idx1,
    const int* __restrict__ idx2,
    const f32x4* __restrict__ w4,   // [VOCAB * 128]
    f32x4* __restrict__ out4,       // [P * 128]
    int total_pairs)                // P * 64
{
    int t = blockIdx.x * blockDim.x + threadIdx.x;
    if (t >= total_pairs) return;

    int pos = t >> 6;            // position — uniform across each 64-lane wave
    int q   = t & 63;            // lane's first quad; second is q+64

    int i1 = __builtin_amdgcn_readfirstlane(idx1[pos]);
    int i2 = __builtin_amdgcn_readfirstlane(idx2[pos]);

    const f32x4* r1 = w4 + (long)i1 * QUADS_PER_ROW;
    f32x4 a = r1[q];
    f32x4 b = r1[q + 64];
    if (i2 != i1) {
        const f32x4* r2 = w4 + (long)i2 * QUADS_PER_ROW;
        a += r2[q];
        b += r2[q + 64];
    }
    f32x4* o = out4 + (long)pos * QUADS_PER_ROW;
    __builtin_nontemporal_store(a, &o[q]);
    __builtin_nontemporal_store(b, &o[q + 64]);
}

extern "C" void kernel_launch(void* const* d_in, const int* in_sizes, int n_in,
                              void* d_out, int out_size, void* d_ws, size_t ws_size,
                              hipStream_t stream) {
    const int*   idx1 = (const int*)d_in[0];    // input_one [B,S] int32
    const int*   idx2 = (const int*)d_in[1];    // input_two [B,S] int32
    const f32x4* w4   = (const f32x4*)d_in[2];  // weight [VOCAB, 512] fp32
    f32x4* out4       = (f32x4*)d_out;          // [B,S,512] fp32

    int total_pairs = out_size / 8;              // P * 64
    int block = 256;
    int grid  = (total_pairs + block - 1) / block;
    twohot_kernel<<<grid, block, 0, stream>>>(idx1, idx2, w4, out4, total_pairs);
}